// Round 1
// baseline (356.775 us; speedup 1.0000x reference)
//
#include <hip/hip_runtime.h>
#include <cfloat>

// Problem constants
#define T_TOTAL 32768   // 32*32*32 spatial positions
#define DIM 64          // embedding dim
#define KCODES 1024     // num embeddings

// d_out flat layout (fp32 elements), reference return order:
//   quantized_out [32,64,32,32] = 2097152
//   loss (1), perplexity (1)
//   encodings [32768,1024] = 33554432
//   distances [32768,1024] = 33554432
static constexpr long long OFF_Q    = 0;
static constexpr long long OFF_LOSS = 2097152;
static constexpr long long OFF_PERP = 2097153;
static constexpr long long OFF_ENC  = 2097154;            // byte offset mod 16 == 8 -> only 8B aligned!
static constexpr long long OFF_DIST = 2097154LL + 33554432LL; // 35651586, also 8B aligned only

// ws layout: [0,4096) int counts[1024]; [4096,8192) float ww[1024]; [8192,8196) float lossSum

// ---------------------------------------------------------------------------
// Precompute ||w_k||^2 for all 1024 codes. One wave per code.
__global__ __launch_bounds__(256) void vq_ww_kernel(const float* __restrict__ W,
                                                    float* __restrict__ ww) {
    const int tid  = threadIdx.x;
    const int lane = tid & 63;
    const int code = blockIdx.x * 4 + (tid >> 6);
    float v = W[code * DIM + lane];
    float s = v * v;
    #pragma unroll
    for (int off = 32; off > 0; off >>= 1)
        s += __shfl_down(s, off, 64);
    if (lane == 0) ww[code] = s;
}

// ---------------------------------------------------------------------------
// Main fused kernel: distances GEMM + argmin + one-hot + gather + loss partial.
// 512 blocks x 256 threads; each block owns 64 consecutive flat rows t.
__global__ __launch_bounds__(256) void vq_main_kernel(const float* __restrict__ lat,
                                                      const float* __restrict__ W,
                                                      const float* __restrict__ ww,
                                                      float* __restrict__ out,
                                                      int* __restrict__ counts,
                                                      float* __restrict__ lossSum) {
    __shared__ float xT[64 * 64];      // [n][tl] — global layout already "transposed", conflict-free
    __shared__ float wS[64 * 65];      // [kl][n] stride 65 (pad kills conflicts); reused as qS[tl*65+n]
    __shared__ float xx[64];           // ||x_row||^2
    __shared__ float redV[64 * 16];
    __shared__ int   redI[64 * 16];
    __shared__ int   selIdx[64];

    const int tid = threadIdx.x;
    const int tx  = tid & 15;          // col group: codes tx*4 .. tx*4+3 within chunk
    const int ty  = tid >> 4;          // row group: rows ty*4 .. ty*4+3
    const int t0  = blockIdx.x * 64;
    // flat row t maps to latent addr b*65536 + n*1024 + (j*32+d); for a 64-row block
    // the (j*32+d) part is contiguous: base + n*1024 + tl
    const long long base = (long long)(t0 >> 10) * 65536 + (long long)(t0 & 1023);

    // ---- stage x tile (16 KB), coalesced 256B per wave, conflict-free LDS writes
    #pragma unroll
    for (int i = 0; i < 16; ++i) {
        int e  = i * 256 + tid;
        int n  = e >> 6;
        int tl = e & 63;
        xT[n * 64 + tl] = lat[base + (long long)n * 1024 + tl];
    }
    __syncthreads();
    if (tid < 64) {
        float s = 0.f;
        #pragma unroll 8
        for (int n = 0; n < 64; ++n) {
            float v = xT[n * 64 + tid];
            s = fmaf(v, v, s);
        }
        xx[tid] = s;
    }

    float minV[4] = {FLT_MAX, FLT_MAX, FLT_MAX, FLT_MAX};
    int   minI[4] = {0, 0, 0, 0};

    float* __restrict__ distOut = out + OFF_DIST;

    for (int c = 0; c < 16; ++c) {
        __syncthreads();   // previous chunk done reading wS (also covers xT on c==0 via 2nd sync)
        // ---- stage W chunk (64 codes x 64 dims): float4 global loads, scalar LDS writes (2-way, free)
        {
            const float4* __restrict__ Wv = (const float4*)(W + c * 4096);
            #pragma unroll
            for (int i = 0; i < 4; ++i) {
                int e2 = i * 256 + tid;          // [0,1024) float4s
                float4 v = Wv[e2];
                int kl = e2 >> 4;
                int n0 = (e2 & 15) * 4;
                float* p = &wS[kl * 65 + n0];
                p[0] = v.x; p[1] = v.y; p[2] = v.z; p[3] = v.w;
            }
        }
        __syncthreads();

        // ---- 4x4 register-tiled fp32 GEMM over this chunk
        float acc[4][4] = {{0.f,0.f,0.f,0.f},{0.f,0.f,0.f,0.f},{0.f,0.f,0.f,0.f},{0.f,0.f,0.f,0.f}};
        #pragma unroll 8
        for (int n = 0; n < 64; ++n) {
            float4 a = *(const float4*)&xT[n * 64 + ty * 4];   // ds_read_b128, broadcast, conflict-free
            float b0 = wS[(tx * 4 + 0) * 65 + n];              // stride-65: 2-way = free
            float b1 = wS[(tx * 4 + 1) * 65 + n];
            float b2 = wS[(tx * 4 + 2) * 65 + n];
            float b3 = wS[(tx * 4 + 3) * 65 + n];
            acc[0][0] = fmaf(a.x, b0, acc[0][0]);
            acc[0][1] = fmaf(a.x, b1, acc[0][1]);
            acc[0][2] = fmaf(a.x, b2, acc[0][2]);
            acc[0][3] = fmaf(a.x, b3, acc[0][3]);
            acc[1][0] = fmaf(a.y, b0, acc[1][0]);
            acc[1][1] = fmaf(a.y, b1, acc[1][1]);
            acc[1][2] = fmaf(a.y, b2, acc[1][2]);
            acc[1][3] = fmaf(a.y, b3, acc[1][3]);
            acc[2][0] = fmaf(a.z, b0, acc[2][0]);
            acc[2][1] = fmaf(a.z, b1, acc[2][1]);
            acc[2][2] = fmaf(a.z, b2, acc[2][2]);
            acc[2][3] = fmaf(a.z, b3, acc[2][3]);
            acc[3][0] = fmaf(a.w, b0, acc[3][0]);
            acc[3][1] = fmaf(a.w, b1, acc[3][1]);
            acc[3][2] = fmaf(a.w, b2, acc[3][2]);
            acc[3][3] = fmaf(a.w, b3, acc[3][3]);
        }

        // ---- distances out + running argmin (np tie semantics: strict <, ascending code order)
        const int kbase = c * 64 + tx * 4;
        float w0 = ww[kbase + 0];
        float w1 = ww[kbase + 1];
        float w2 = ww[kbase + 2];
        float w3 = ww[kbase + 3];
        #pragma unroll
        for (int qr = 0; qr < 4; ++qr) {
            const int row = ty * 4 + qr;
            const float xxr = xx[row];
            float d0 = (xxr + w0) - 2.f * acc[qr][0];
            float d1 = (xxr + w1) - 2.f * acc[qr][1];
            float d2 = (xxr + w2) - 2.f * acc[qr][2];
            float d3 = (xxr + w3) - 2.f * acc[qr][3];
            if (d0 < minV[qr]) { minV[qr] = d0; minI[qr] = kbase + 0; }
            if (d1 < minV[qr]) { minV[qr] = d1; minI[qr] = kbase + 1; }
            if (d2 < minV[qr]) { minV[qr] = d2; minI[qr] = kbase + 2; }
            if (d3 < minV[qr]) { minV[qr] = d3; minI[qr] = kbase + 3; }
            const long long ro = (long long)(t0 + row) * KCODES + kbase;
            *(float2*)&distOut[ro]     = make_float2(d0, d1);   // d_out dist region is 8B aligned only
            *(float2*)&distOut[ro + 2] = make_float2(d2, d3);
        }
    }

    // ---- cross-thread argmin reduction (prefer lower index on exact ties)
    #pragma unroll
    for (int qr = 0; qr < 4; ++qr) {
        const int row = ty * 4 + qr;
        redV[row * 16 + tx] = minV[qr];
        redI[row * 16 + tx] = minI[qr];
    }
    __syncthreads();
    if (tid < 64) {
        float best = redV[tid * 16];
        int   bi   = redI[tid * 16];
        #pragma unroll
        for (int s = 1; s < 16; ++s) {
            float v  = redV[tid * 16 + s];
            int   i2 = redI[tid * 16 + s];
            if (v < best || (v == best && i2 < bi)) { best = v; bi = i2; }
        }
        selIdx[tid] = bi;
        atomicAdd(&counts[bi], 1);
    }
    __syncthreads();

    // ---- gather selected codebook rows into LDS (coalesced 256B per wave), stride 65
    float* qS = wS;  // reuse
    #pragma unroll
    for (int i = 0; i < 16; ++i) {
        int e   = i * 256 + tid;
        int row = e >> 6;
        int n   = e & 63;
        qS[row * 65 + n] = W[selIdx[row] * DIM + n];
    }
    __syncthreads();

    // ---- quantized_out (float4, 16B aligned) + loss partial
    float ls = 0.f;
    #pragma unroll
    for (int i = 0; i < 4; ++i) {
        int e2  = i * 256 + tid;       // [0,1024) float4s
        int n   = e2 >> 4;
        int tl0 = (e2 & 15) * 4;
        float q0 = qS[(tl0 + 0) * 65 + n];
        float q1 = qS[(tl0 + 1) * 65 + n];
        float q2 = qS[(tl0 + 2) * 65 + n];
        float q3 = qS[(tl0 + 3) * 65 + n];
        float x0 = xT[n * 64 + tl0 + 0];
        float x1 = xT[n * 64 + tl0 + 1];
        float x2 = xT[n * 64 + tl0 + 2];
        float x3 = xT[n * 64 + tl0 + 3];
        *(float4*)&out[OFF_Q + base + (long long)n * 1024 + tl0] = make_float4(q0, q1, q2, q3);
        float e0 = q0 - x0; ls = fmaf(e0, e0, ls);
        float e1 = q1 - x1; ls = fmaf(e1, e1, ls);
        float e2d = q2 - x2; ls = fmaf(e2d, e2d, ls);
        float e3 = q3 - x3; ls = fmaf(e3, e3, ls);
    }
    #pragma unroll
    for (int off = 32; off > 0; off >>= 1)
        ls += __shfl_down(ls, off, 64);
    if ((tid & 63) == 0) atomicAdd(lossSum, ls);

    // ---- one-hot encodings: 64 rows x 1024 cols, float2 stores (region only 8B aligned)
    float* __restrict__ enc = out + OFF_ENC;
    for (int i = 0; i < 128; ++i) {
        int e2  = i * 256 + tid;       // [0,32768) float2s
        int row = e2 >> 9;             // 512 float2 per row
        int k2  = (e2 & 511) * 2;
        int sel = selIdx[row];
        float2 v;
        v.x = (k2     == sel) ? 1.f : 0.f;
        v.y = (k2 + 1 == sel) ? 1.f : 0.f;
        *(float2*)&enc[(long long)(t0 + row) * KCODES + k2] = v;
    }
}

// ---------------------------------------------------------------------------
// Finalize: perplexity from histogram, loss from accumulated SSE.
__global__ __launch_bounds__(1024) void vq_finalize_kernel(const int* __restrict__ counts,
                                                           const float* __restrict__ lossSum,
                                                           float* __restrict__ out) {
    __shared__ float red[16];
    const int tid = threadIdx.x;
    float p = (float)counts[tid] * (1.0f / 32768.0f);   // exact (pow2 divisor)
    float term = p * logf(p + 1e-10f);
    #pragma unroll
    for (int off = 32; off > 0; off >>= 1)
        term += __shfl_down(term, off, 64);
    if ((tid & 63) == 0) red[tid >> 6] = term;
    __syncthreads();
    if (tid == 0) {
        float s = 0.f;
        #pragma unroll
        for (int i = 0; i < 16; ++i) s += red[i];
        out[OFF_PERP] = expf(-s);
        out[OFF_LOSS] = 0.25f * lossSum[0] * (1.0f / 2097152.0f);  // COMMIT_COST * mean SSE
    }
}

// ---------------------------------------------------------------------------
extern "C" void kernel_launch(void* const* d_in, const int* in_sizes, int n_in,
                              void* d_out, int out_size, void* d_ws, size_t ws_size,
                              hipStream_t stream) {
    (void)in_sizes; (void)n_in; (void)out_size; (void)ws_size;
    const float* lat = (const float*)d_in[0];   // [32,64,32,32]
    const float* W   = (const float*)d_in[1];   // [1024,64]
    float* out = (float*)d_out;

    int*   counts  = (int*)d_ws;
    float* ww      = (float*)((char*)d_ws + 4096);
    float* lossSum = (float*)((char*)d_ws + 8192);

    // zero counts + lossSum (ww is fully overwritten by vq_ww_kernel)
    hipMemsetAsync(d_ws, 0, 8192 + 16, stream);

    vq_ww_kernel<<<256, 256, 0, stream>>>(W, ww);
    vq_main_kernel<<<512, 256, 0, stream>>>(lat, W, ww, out, counts, lossSum);
    vq_finalize_kernel<<<1, 1024, 0, stream>>>(counts, lossSum, out);
}

// Round 2
// 340.247 us; speedup vs baseline: 1.0486x; 1.0486x over previous
//
#include <hip/hip_runtime.h>
#include <cfloat>

// Problem constants
#define T_TOTAL 32768   // 32*32*32 spatial positions
#define DIM 64          // embedding dim
#define KCODES 1024     // num embeddings

// d_out flat layout (fp32 elements), reference return order:
//   quantized_out [32,64,32,32] = 2097152
//   loss (1), perplexity (1)
//   encodings [32768,1024] = 33554432
//   distances [32768,1024] = 33554432
static constexpr long long OFF_Q    = 0;
static constexpr long long OFF_LOSS = 2097152;
static constexpr long long OFF_PERP = 2097153;
static constexpr long long OFF_ENC  = 2097154;            // byte offset mod 16 == 8 -> only 8B aligned!
static constexpr long long OFF_DIST = 2097154LL + 33554432LL; // also 8B aligned only

// ws layout: [0,4096) int counts[1024]; [4096,8192) float ww[1024];
//            [8192,8196) float lossSum; [12288, 12288+256K) float WT[64][1024]

// ---------------------------------------------------------------------------
// Prep: ||w_k||^2 for all codes (blocks 0..255) + W transpose WT[n][k] (blocks 256..319).
__global__ __launch_bounds__(256) void vq_prep_kernel(const float* __restrict__ W,
                                                      float* __restrict__ ww,
                                                      float* __restrict__ WT) {
    const int tid = threadIdx.x;
    if (blockIdx.x < 256) {
        const int lane = tid & 63;
        const int code = blockIdx.x * 4 + (tid >> 6);
        float v = W[code * DIM + lane];
        float s = v * v;
        #pragma unroll
        for (int off = 32; off > 0; off >>= 1)
            s += __shfl_down(s, off, 64);
        if (lane == 0) ww[code] = s;
    } else {
        const int n = blockIdx.x - 256;   // 0..63
        #pragma unroll
        for (int i = 0; i < 4; ++i) {
            int k = i * 256 + tid;
            WT[n * KCODES + k] = W[k * DIM + n];
        }
    }
}

// ---------------------------------------------------------------------------
// Main fused kernel: distances GEMM + argmin + one-hot + gather + loss partial.
// 512 blocks x 256 threads; each block owns 64 consecutive flat rows t.
// Micro-tile: 8 rows x 8 codes per thread (2x float4 per operand, all-b128 LDS).
__global__ __launch_bounds__(256, 3) void vq_main_kernel(const float* __restrict__ lat,
                                                         const float* __restrict__ W,
                                                         const float* __restrict__ ww,
                                                         const float* __restrict__ WT,
                                                         float* __restrict__ out,
                                                         int* __restrict__ counts,
                                                         float* __restrict__ lossSum) {
    __shared__ float xT[64 * 64];      // [n][tl] 16 KB — persistent across kernel
    __shared__ float wS[32 * 256];     // [n][k] 32 KB — GEMM staging; reused for red/qS
    __shared__ float xx[64];           // ||x_row||^2
    __shared__ int   selIdx[64];

    const int tid = threadIdx.x;
    const int tx  = tid & 31;          // code groups: tx*4..+3 and 128+tx*4..+3 (per chunk)
    const int ty  = tid >> 5;          // row groups:  ty*4..+3 and 32+ty*4..+3
    const int t0  = blockIdx.x * 64;
    // flat row t maps to latent addr b*65536 + n*1024 + (j*32+d); for a 64-row block
    // the (j*32+d) part is contiguous: base + n*1024 + tl
    const long long base = (long long)(t0 >> 10) * 65536 + (long long)(t0 & 1023);

    // ---- stage x tile (16 KB), coalesced global reads, conflict-free LDS writes
    #pragma unroll
    for (int i = 0; i < 16; ++i) {
        int e  = i * 256 + tid;
        int n  = e >> 6;
        int tl = e & 63;
        xT[n * 64 + tl] = lat[base + (long long)n * 1024 + tl];
    }
    __syncthreads();
    if (tid < 64) {
        float s = 0.f;
        #pragma unroll 8
        for (int n = 0; n < 64; ++n) {
            float v = xT[n * 64 + tid];
            s = fmaf(v, v, s);
        }
        xx[tid] = s;
    }

    float minV[8];
    int   minI[8];
    #pragma unroll
    for (int r = 0; r < 8; ++r) { minV[r] = FLT_MAX; minI[r] = 0; }

    float* __restrict__ distOut = out + OFF_DIST;

    for (int c = 0; c < 4; ++c) {      // 4 chunks of 256 codes
        float acc[8][8];
        #pragma unroll
        for (int r = 0; r < 8; ++r)
            #pragma unroll
            for (int k = 0; k < 8; ++k) acc[r][k] = 0.f;

        for (int h = 0; h < 2; ++h) {  // n-halves of 32 (LDS capacity)
            __syncthreads();           // previous phase done reading wS
            // ---- stage WT[h*32.., c*256..] -> wS[n][k]: coalesced f4 reads, b128 writes
            #pragma unroll
            for (int i = 0; i < 8; ++i) {
                int e2 = i * 256 + tid;            // [0,2048) float4s
                int n  = e2 >> 6;                  // 0..31
                int k4 = e2 & 63;
                *(float4*)&wS[n * 256 + k4 * 4] =
                    *(const float4*)&WT[(h * 32 + n) * KCODES + c * 256 + k4 * 4];
            }
            __syncthreads();

            // ---- 8x8 register-tiled fp32 GEMM over this n-half
            #pragma unroll 4
            for (int nn = 0; nn < 32; ++nn) {
                const float* xrow = &xT[(h * 32 + nn) * 64];
                const float* wrow = &wS[nn * 256];
                float4 a0 = *(const float4*)&xrow[ty * 4];        // broadcast (free)
                float4 a1 = *(const float4*)&xrow[32 + ty * 4];
                float4 b0 = *(const float4*)&wrow[tx * 4];        // contiguous b128
                float4 b1 = *(const float4*)&wrow[128 + tx * 4];
                float ar[8] = {a0.x, a0.y, a0.z, a0.w, a1.x, a1.y, a1.z, a1.w};
                float br[8] = {b0.x, b0.y, b0.z, b0.w, b1.x, b1.y, b1.z, b1.w};
                #pragma unroll
                for (int r = 0; r < 8; ++r)
                    #pragma unroll
                    for (int k = 0; k < 8; ++k)
                        acc[r][k] = fmaf(ar[r], br[k], acc[r][k]);
            }
        }

        // ---- distances out + running argmin (np tie semantics: strict <, ascending k)
        // thread's codes: k = c*256 + (kk>>2)*128 + tx*4 + (kk&3) — ascending in kk
        const int kb0 = c * 256 + tx * 4;
        float wr[8];
        #pragma unroll
        for (int k = 0; k < 8; ++k)
            wr[k] = ww[kb0 + (k >> 2) * 128 + (k & 3)];
        #pragma unroll
        for (int r = 0; r < 8; ++r) {
            const int row = (r >> 2) * 32 + ty * 4 + (r & 3);
            const float xxr = xx[row];
            float d[8];
            #pragma unroll
            for (int k = 0; k < 8; ++k) {
                d[k] = (xxr + wr[k]) - 2.f * acc[r][k];
                int ki = kb0 + (k >> 2) * 128 + (k & 3);
                if (d[k] < minV[r]) { minV[r] = d[k]; minI[r] = ki; }
            }
            const long long ro = (long long)(t0 + row) * KCODES + kb0;
            *(float2*)&distOut[ro]           = make_float2(d[0], d[1]);
            *(float2*)&distOut[ro + 2]       = make_float2(d[2], d[3]);
            *(float2*)&distOut[ro + 128]     = make_float2(d[4], d[5]);
            *(float2*)&distOut[ro + 130]     = make_float2(d[6], d[7]);
        }
    }

    // ---- cross-thread argmin reduction (32 candidates per row), alias wS
    __syncthreads();                   // all GEMM reads of wS done
    float* redV = wS;                  // [64][33] padded -> conflict-free scan
    int*   redI = (int*)(wS + 64 * 33);
    #pragma unroll
    for (int r = 0; r < 8; ++r) {
        const int row = (r >> 2) * 32 + ty * 4 + (r & 3);
        redV[row * 33 + tx] = minV[r];
        redI[row * 33 + tx] = minI[r];
    }
    __syncthreads();
    if (tid < 64) {
        float best = redV[tid * 33];
        int   bi   = redI[tid * 33];
        #pragma unroll
        for (int s = 1; s < 32; ++s) {
            float v  = redV[tid * 33 + s];
            int   i2 = redI[tid * 33 + s];
            if (v < best || (v == best && i2 < bi)) { best = v; bi = i2; }
        }
        selIdx[tid] = bi;
        atomicAdd(&counts[bi], 1);
    }
    __syncthreads();

    // ---- gather selected codebook rows into LDS (coalesced), stride 65 kills conflicts
    float* qS = wS;  // reuse (scan done)
    #pragma unroll
    for (int i = 0; i < 16; ++i) {
        int e   = i * 256 + tid;
        int row = e >> 6;
        int n   = e & 63;
        qS[row * 65 + n] = W[selIdx[row] * DIM + n];
    }
    __syncthreads();

    // ---- quantized_out (float4, 16B aligned) + loss partial
    float ls = 0.f;
    #pragma unroll
    for (int i = 0; i < 4; ++i) {
        int e2  = i * 256 + tid;       // [0,1024) float4s
        int n   = e2 >> 4;
        int tl0 = (e2 & 15) * 4;
        float q0 = qS[(tl0 + 0) * 65 + n];
        float q1 = qS[(tl0 + 1) * 65 + n];
        float q2 = qS[(tl0 + 2) * 65 + n];
        float q3 = qS[(tl0 + 3) * 65 + n];
        float x0 = xT[n * 64 + tl0 + 0];
        float x1 = xT[n * 64 + tl0 + 1];
        float x2 = xT[n * 64 + tl0 + 2];
        float x3 = xT[n * 64 + tl0 + 3];
        *(float4*)&out[OFF_Q + base + (long long)n * 1024 + tl0] = make_float4(q0, q1, q2, q3);
        float e0 = q0 - x0; ls = fmaf(e0, e0, ls);
        float e1 = q1 - x1; ls = fmaf(e1, e1, ls);
        float e2d = q2 - x2; ls = fmaf(e2d, e2d, ls);
        float e3 = q3 - x3; ls = fmaf(e3, e3, ls);
    }
    #pragma unroll
    for (int off = 32; off > 0; off >>= 1)
        ls += __shfl_down(ls, off, 64);
    if ((tid & 63) == 0) atomicAdd(lossSum, ls);

    // ---- one-hot encodings: 64 rows x 1024 cols, float2 stores (region only 8B aligned)
    float* __restrict__ enc = out + OFF_ENC;
    for (int i = 0; i < 128; ++i) {
        int e2  = i * 256 + tid;       // [0,32768) float2s
        int row = e2 >> 9;             // 512 float2 per row
        int k2  = (e2 & 511) * 2;
        int sel = selIdx[row];
        float2 v;
        v.x = (k2     == sel) ? 1.f : 0.f;
        v.y = (k2 + 1 == sel) ? 1.f : 0.f;
        *(float2*)&enc[(long long)(t0 + row) * KCODES + k2] = v;
    }
}

// ---------------------------------------------------------------------------
// Finalize: perplexity from histogram, loss from accumulated SSE.
__global__ __launch_bounds__(1024) void vq_finalize_kernel(const int* __restrict__ counts,
                                                           const float* __restrict__ lossSum,
                                                           float* __restrict__ out) {
    __shared__ float red[16];
    const int tid = threadIdx.x;
    float p = (float)counts[tid] * (1.0f / 32768.0f);   // exact (pow2 divisor)
    float term = p * logf(p + 1e-10f);
    #pragma unroll
    for (int off = 32; off > 0; off >>= 1)
        term += __shfl_down(term, off, 64);
    if ((tid & 63) == 0) red[tid >> 6] = term;
    __syncthreads();
    if (tid == 0) {
        float s = 0.f;
        #pragma unroll
        for (int i = 0; i < 16; ++i) s += red[i];
        out[OFF_PERP] = expf(-s);
        out[OFF_LOSS] = 0.25f * lossSum[0] * (1.0f / 2097152.0f);  // COMMIT_COST * mean SSE
    }
}

// ---------------------------------------------------------------------------
extern "C" void kernel_launch(void* const* d_in, const int* in_sizes, int n_in,
                              void* d_out, int out_size, void* d_ws, size_t ws_size,
                              hipStream_t stream) {
    (void)in_sizes; (void)n_in; (void)out_size; (void)ws_size;
    const float* lat = (const float*)d_in[0];   // [32,64,32,32]
    const float* W   = (const float*)d_in[1];   // [1024,64]
    float* out = (float*)d_out;

    int*   counts  = (int*)d_ws;
    float* ww      = (float*)((char*)d_ws + 4096);
    float* lossSum = (float*)((char*)d_ws + 8192);
    float* WT      = (float*)((char*)d_ws + 12288);   // 64x1024 fp32 = 256 KB

    // zero counts + lossSum (ww/WT fully overwritten by vq_prep_kernel)
    hipMemsetAsync(d_ws, 0, 8192 + 16, stream);

    vq_prep_kernel<<<320, 256, 0, stream>>>(W, ww, WT);
    vq_main_kernel<<<512, 256, 0, stream>>>(lat, W, ww, WT, out, counts, lossSum);
    vq_finalize_kernel<<<1, 1024, 0, stream>>>(counts, lossSum, out);
}